// Round 4
// baseline (124.031 us; speedup 1.0000x reference)
//
#include <hip/hip_runtime.h>

// Problem: trilinear warp (SpatialTransformer) of vol [B=2,D=160,H=192,W=160,C=2] f32
// by dense flow [B,D,H,W,3] f32 ('ij' indexing). Output f32, same shape as vol.
// Memory-bound: ~275 MB min traffic/call -> ~44 us floor at 6.3 TB/s.

constexpr int Bb = 2;
constexpr int Dd = 160;
constexpr int Hh = 192;
constexpr int Ww = 160;
constexpr int Cc = 2;
constexpr int HW  = Hh * Ww;          // 30720
constexpr int VOX = Dd * HW;          // 4,915,200 voxels per batch
constexpr int TOTAL = Bb * VOX;       // 9,830,400 voxels total (= 38400 * 256)

__global__ __launch_bounds__(256)
void SpatialTransformer_44418551776013_kernel(const float* __restrict__ vol,
                                              const float* __restrict__ flow,
                                              float* __restrict__ out)
{
    const int g = blockIdx.x * 256 + threadIdx.x;   // grid sized exactly; no tail
    // decompose g -> (b, d, h, w)
    const int b   = g / VOX;
    const int r   = g - b * VOX;
    const int d   = r / HW;
    const int rem = r - d * HW;
    const int h   = rem / Ww;
    const int w   = rem - h * Ww;

    // flow: 3 contiguous f32 per voxel (coalesced 12 B/lane)
    const float* f = flow + (size_t)g * 3;
    const float lx = (float)d + f[0];
    const float ly = (float)h + f[1];
    const float lz = (float)w + f[2];

    // Reference semantics, exactly:
    //   loc0 = clip(floor(loc), 0, max); loc1 = clip(loc0 + 1, 0, max)
    //   d1 = loc1 - loc (weight for lower corner); d0 = 1 - d1 (upper corner)
    //   NO clamping of the weights themselves.
    const float mx = (float)(Dd - 1), my = (float)(Hh - 1), mz = (float)(Ww - 1);

    const float l0x = fminf(fmaxf(floorf(lx), 0.0f), mx);
    const float l0y = fminf(fmaxf(floorf(ly), 0.0f), my);
    const float l0z = fminf(fmaxf(floorf(lz), 0.0f), mz);
    const float l1x = fminf(l0x + 1.0f, mx);   // l0 >= 0 -> lower clip of loc1 is a no-op
    const float l1y = fminf(l0y + 1.0f, my);
    const float l1z = fminf(l0z + 1.0f, mz);

    const float d1x = l1x - lx, d0x = 1.0f - d1x;
    const float d1y = l1y - ly, d0y = 1.0f - d1y;
    const float d1z = l1z - lz, d0z = 1.0f - d1z;

    const int i0x = (int)l0x, i1x = (int)l1x;
    const int i0y = (int)l0y, i1y = (int)l1y;
    const int i0z = (int)l0z, i1z = (int)l1z;

    // C == 2 -> each corner is one contiguous float2 (8 B) gather
    const float2* __restrict__ v2 =
        reinterpret_cast<const float2*>(vol + (size_t)b * (size_t)VOX * Cc);

    const int rx0 = i0x * HW, rx1 = i1x * HW;
    const int ry0 = i0y * Ww, ry1 = i1y * Ww;

    const float2 c000 = v2[rx0 + ry0 + i0z];
    const float2 c001 = v2[rx0 + ry0 + i1z];
    const float2 c010 = v2[rx0 + ry1 + i0z];
    const float2 c011 = v2[rx0 + ry1 + i1z];
    const float2 c100 = v2[rx1 + ry0 + i0z];
    const float2 c101 = v2[rx1 + ry0 + i1z];
    const float2 c110 = v2[rx1 + ry1 + i0z];
    const float2 c111 = v2[rx1 + ry1 + i1z];

    // corner bit 0 -> lower index, weight d1; bit 1 -> upper index, weight d0
    const float w000 = d1x * d1y * d1z;
    const float w001 = d1x * d1y * d0z;
    const float w010 = d1x * d0y * d1z;
    const float w011 = d1x * d0y * d0z;
    const float w100 = d0x * d1y * d1z;
    const float w101 = d0x * d1y * d0z;
    const float w110 = d0x * d0y * d1z;
    const float w111 = d0x * d0y * d0z;

    float ox = w000 * c000.x;
    float oy = w000 * c000.y;
    ox = fmaf(w001, c001.x, ox);  oy = fmaf(w001, c001.y, oy);
    ox = fmaf(w010, c010.x, ox);  oy = fmaf(w010, c010.y, oy);
    ox = fmaf(w011, c011.x, ox);  oy = fmaf(w011, c011.y, oy);
    ox = fmaf(w100, c100.x, ox);  oy = fmaf(w100, c100.y, oy);
    ox = fmaf(w101, c101.x, ox);  oy = fmaf(w101, c101.y, oy);
    ox = fmaf(w110, c110.x, ox);  oy = fmaf(w110, c110.y, oy);
    ox = fmaf(w111, c111.x, ox);  oy = fmaf(w111, c111.y, oy);

    // coalesced 8 B/lane store
    reinterpret_cast<float2*>(out)[g] = make_float2(ox, oy);
}

extern "C" void kernel_launch(void* const* d_in, const int* in_sizes, int n_in,
                              void* d_out, int out_size, void* d_ws, size_t ws_size,
                              hipStream_t stream)
{
    const float* vol  = (const float*)d_in[0];   // [2,160,192,160,2] f32
    const float* flow = (const float*)d_in[1];   // [2,160,192,160,3] f32
    float* out = (float*)d_out;                  // [2,160,192,160,2] f32

    constexpr int block = 256;
    constexpr int grid  = TOTAL / block;         // 38400, exact — no tail guard needed
    SpatialTransformer_44418551776013_kernel<<<grid, block, 0, stream>>>(vol, flow, out);
}

// Round 5
// 121.881 us; speedup vs baseline: 1.0176x; 1.0176x over previous
//
#include <hip/hip_runtime.h>

// Trilinear warp (SpatialTransformer): vol [B=2,D=160,H=192,W=160,C=2] f32,
// flow [B,D,H,W,3] f32 ('ij'). Output f32 same shape as vol.
//
// Bottleneck (R4 profile): L1 gather-transaction rate, not HBM BW.
// Flow jitter scatters each wave's 64 lanes onto ~64 distinct cache lines per
// gather, so 8 gathers/voxel => ~78.6M line-transactions ~= 128us at
// 1 txn/cy/CU. This version fuses each z-corner pair (adjacent float2s) into
// one 16B dwordx4 gather => 4 gathers/voxel. z-top clamp handled via weights.

constexpr int Bb = 2;
constexpr int Dd = 160;
constexpr int Hh = 192;
constexpr int Ww = 160;
constexpr int Cc = 2;
constexpr int HW  = Hh * Ww;          // 30720
constexpr int VOX = Dd * HW;          // 4,915,200 voxels per batch
constexpr int TOTAL = Bb * VOX;       // 9,830,400 voxels (= 38400 * 256)

__global__ __launch_bounds__(256)
void SpatialTransformer_44418551776013_kernel(const float* __restrict__ vol,
                                              const float* __restrict__ flow,
                                              float* __restrict__ out)
{
    const int g = blockIdx.x * 256 + threadIdx.x;   // grid exact, no tail
    const int b   = g / VOX;
    const int r   = g - b * VOX;
    const int d   = r / HW;
    const int rem = r - d * HW;
    const int h   = rem / Ww;
    const int w   = rem - h * Ww;

    // flow: 3 contiguous f32 per voxel (coalesced)
    const float* f = flow + (size_t)g * 3;
    const float lx = (float)d + f[0];
    const float ly = (float)h + f[1];
    const float lz = (float)w + f[2];

    // Reference semantics:
    //   loc0 = clip(floor(loc), 0, max); loc1 = clip(loc0 + 1, 0, max)
    //   d1 = loc1 - loc (lower-corner weight); d0 = 1 - d1 (upper-corner)
    //   weights themselves NOT clamped (extrapolation allowed).
    const float mx = (float)(Dd - 1), my = (float)(Hh - 1), mz = (float)(Ww - 1);

    const float l0x = fminf(fmaxf(floorf(lx), 0.0f), mx);
    const float l0y = fminf(fmaxf(floorf(ly), 0.0f), my);
    const float l0z = fminf(fmaxf(floorf(lz), 0.0f), mz);
    const float l1x = fminf(l0x + 1.0f, mx);
    const float l1y = fminf(l0y + 1.0f, my);
    const float l1z = fminf(l0z + 1.0f, mz);

    const float d1x = l1x - lx, d0x = 1.0f - d1x;
    const float d1y = l1y - ly, d0y = 1.0f - d1y;
    const float d1z = l1z - lz, d0z = 1.0f - d1z;

    const int i0x = (int)l0x, i1x = (int)l1x;
    const int i0y = (int)l0y, i1y = (int)l1y;
    const int i0z = (int)l0z;

    // z-pair fusion: one float4 covers c[zbase] (.xy) and c[zbase+1] (.zw).
    // Normal case (i0z <= W-2): zbase=i0z, lower=.xy w/ d1z, upper=.zw w/ d0z.
    // Top clamp (i0z == W-1, so i1z == i0z): zbase=W-2; put ALL weight
    // (d1z+d0z) on .zw (= c[W-1], the correct clamped value) and 0 on .xy.
    // 0 * finite = 0 exactly; combined weight differs from the reference's
    // two-term sum by <=1 ulp.
    const bool  ztop  = (i0z == Ww - 1);
    const int   zbase = ztop ? (Ww - 2) : i0z;
    const float wzl   = ztop ? 0.0f : d1z;          // weight on .xy
    const float wzh   = ztop ? (d1z + d0z) : d0z;   // weight on .zw

    const float2* __restrict__ v2 =
        reinterpret_cast<const float2*>(vol + (size_t)b * (size_t)VOX * Cc);

    const int rx0 = i0x * HW, rx1 = i1x * HW;
    const int ry0 = i0y * Ww, ry1 = i1y * Ww;

    // 4 × 16B gathers (dword-aligned; multi-dword global loads need only
    // dword alignment on CDNA). Issue all before consuming for MLP.
    const float4 q00 = *reinterpret_cast<const float4*>(v2 + (rx0 + ry0 + zbase));
    const float4 q01 = *reinterpret_cast<const float4*>(v2 + (rx0 + ry1 + zbase));
    const float4 q10 = *reinterpret_cast<const float4*>(v2 + (rx1 + ry0 + zbase));
    const float4 q11 = *reinterpret_cast<const float4*>(v2 + (rx1 + ry1 + zbase));

    // corner weights (x,y parts exactly as reference)
    const float w00l = d1x * d1y * wzl;   // (x0,y0,z0)
    const float w00h = d1x * d1y * wzh;   // (x0,y0,z1)
    const float w01l = d1x * d0y * wzl;   // (x0,y1,z0)
    const float w01h = d1x * d0y * wzh;   // (x0,y1,z1)
    const float w10l = d0x * d1y * wzl;   // (x1,y0,z0)
    const float w10h = d0x * d1y * wzh;   // (x1,y0,z1)
    const float w11l = d0x * d0y * wzl;   // (x1,y1,z0)
    const float w11h = d0x * d0y * wzh;   // (x1,y1,z1)

    float ox = w00l * q00.x;
    float oy = w00l * q00.y;
    ox = fmaf(w00h, q00.z, ox);  oy = fmaf(w00h, q00.w, oy);
    ox = fmaf(w01l, q01.x, ox);  oy = fmaf(w01l, q01.y, oy);
    ox = fmaf(w01h, q01.z, ox);  oy = fmaf(w01h, q01.w, oy);
    ox = fmaf(w10l, q10.x, ox);  oy = fmaf(w10l, q10.y, oy);
    ox = fmaf(w10h, q10.z, ox);  oy = fmaf(w10h, q10.w, oy);
    ox = fmaf(w11l, q11.x, ox);  oy = fmaf(w11l, q11.y, oy);
    ox = fmaf(w11h, q11.z, ox);  oy = fmaf(w11h, q11.w, oy);

    reinterpret_cast<float2*>(out)[g] = make_float2(ox, oy);
}

extern "C" void kernel_launch(void* const* d_in, const int* in_sizes, int n_in,
                              void* d_out, int out_size, void* d_ws, size_t ws_size,
                              hipStream_t stream)
{
    const float* vol  = (const float*)d_in[0];   // [2,160,192,160,2] f32
    const float* flow = (const float*)d_in[1];   // [2,160,192,160,3] f32
    float* out = (float*)d_out;                  // [2,160,192,160,2] f32

    constexpr int block = 256;
    constexpr int grid  = TOTAL / block;         // 38400, exact
    SpatialTransformer_44418551776013_kernel<<<grid, block, 0, stream>>>(vol, flow, out);
}